// Round 16
// baseline (212.669 us; speedup 1.0000x reference)
//
#include <hip/hip_runtime.h>
#include <stdint.h>

#define HEADS 16
#define HD 128
#define S_TXT 256
#define S_IMG 2048
#define S_ALL 2304
#define DMODEL 2048
#define N_QKV 6144
#define INNER 2048
#define ATT_EPS 1e-5f
#define ATT_SCALE 0.08838834764831845f
#define LOG2E 1.4426950408889634f
#define MBOUND 16.5f
#define QT_N 18      // 2304 / 128
#define TPS 18       // KV tiles (of 32) per split (4 splits)

typedef __attribute__((ext_vector_type(8))) __bf16 bf16x8;
typedef __attribute__((ext_vector_type(4))) float f32x4;
typedef __attribute__((ext_vector_type(4))) uint32_t u32x4;

__device__ __forceinline__ uint16_t f2bf(float f) {
  union { float f; uint32_t u; } v; v.f = f;
  uint32_t r = (v.u + 0x7FFF + ((v.u >> 16) & 1)) >> 16;
  return (uint16_t)r;
}
__device__ __forceinline__ float bf2f(uint16_t h) {
  union { float f; uint32_t u; } v; v.u = ((uint32_t)h) << 16;
  return v.f;
}
// packed fp32x2 -> bf16x2 (RNE), single VALU op; no builtin on gfx950
__device__ __forceinline__ uint32_t cvt_pk_bf16(float lo, float hi) {
  uint32_t r;
  asm("v_cvt_pk_bf16_f32 %0, %1, %2" : "=v"(r) : "v"(lo), "v"(hi));
  return r;
}
__device__ __forceinline__ float fexp2(float x) {
#if __has_builtin(__builtin_amdgcn_exp2f)
  return __builtin_amdgcn_exp2f(x);
#else
  return __expf(x * 0.69314718055994531f);
#endif
}

// async global->LDS, 16B per lane; lds ptr is wave-uniform base (HW adds lane*16)
__device__ __forceinline__ void async_cp16(const void* g, void* l) {
  __builtin_amdgcn_global_load_lds(
      (const __attribute__((address_space(1))) void*)g,
      (__attribute__((address_space(3))) void*)l, 16, 0, 0);
}

// ---------------- prep: 4 transposing weight converts (256x64 tiles, bf16 LDS,
// XOR-chunk swizzle) + 2 straight converts, one launch ----------------
// dst[C][R] = bf16(src[R][C]).  256x64 tile -> 512B-contiguous writes per dst row
// (4x DRAM page locality vs 64x64/128B).  LDS value (r,c) stored at halfword
// r*64 + ((c>>2)^((r>>3)&15))*4 + (c&3): phase-1 writes conflict-free, phase-2
// column gathers <=4-way.
__global__ __launch_bounds__(256) void k_prep(
    const float* __restrict__ s0, uint16_t* __restrict__ d0,
    const float* __restrict__ s1, uint16_t* __restrict__ d1,
    const float* __restrict__ s2, uint16_t* __restrict__ d2,
    const float* __restrict__ s3, uint16_t* __restrict__ d3,
    const float* __restrict__ c0, uint16_t* __restrict__ e0, int n40,
    const float* __restrict__ c1, uint16_t* __restrict__ e1, int n41) {
  __shared__ uint16_t t[256 * 64];
  int b = blockIdx.x;
  if (b >= 2048) {  // straight converts
    const float* src; uint16_t* dst; int n4, bid, nb;
    if (b < 3072) { src = c0; dst = e0; n4 = n40; bid = b - 2048; nb = 1024; }
    else { src = c1; dst = e1; n4 = n41; bid = b - 3072; nb = 128; }
    int i = bid * 256 + threadIdx.x;
    int stride = nb * 256;
    for (; i < n4; i += stride) {
      float4 v = ((const float4*)src)[i];
      uint2 o;
      o.x = cvt_pk_bf16(v.x, v.y);
      o.y = cvt_pk_bf16(v.z, v.w);
      ((uint2*)dst)[i] = o;
    }
    return;
  }
  const float* src; uint16_t* dst; int R, C, tb;
  if (b < 768)       { src = s0; dst = d0; R = DMODEL; C = N_QKV;  tb = b; }
  else if (b < 1536) { src = s1; dst = d1; R = DMODEL; C = N_QKV;  tb = b - 768; }
  else if (b < 1792) { src = s2; dst = d2; R = INNER;  C = DMODEL; tb = b - 1536; }
  else               { src = s3; dst = d3; R = INNER;  C = DMODEL; tb = b - 1792; }
  int ntr = R >> 8;
  int tr = tb % ntr, tc = tb / ntr;
  int tid = threadIdx.x;
  // phase 1: load 256 rows x 64 cols fp32 (coalesced 256B/row), cvt, LDS write
#pragma unroll
  for (int j = 0; j < 16; ++j) {
    int idx = j * 256 + tid;
    int r = idx >> 4, c4 = (idx & 15) * 4;
    float4 v = *(const float4*)&src[(size_t)(tr * 256 + r) * C + tc * 64 + c4];
    uint2 o;
    o.x = cvt_pk_bf16(v.x, v.y);
    o.y = cvt_pk_bf16(v.z, v.w);
    int swz = ((c4 >> 2) ^ ((r >> 3) & 15)) << 2;
    *(uint2*)&t[r * 64 + swz] = o;
  }
  __syncthreads();
  // phase 2: write 64 dst rows x 512B contiguous (32 threads x 16B per row)
#pragma unroll
  for (int j = 0; j < 8; ++j) {
    int idx = j * 256 + tid;
    int c = idx >> 5, r8 = (idx & 31) * 8;
    int chunkbase = (((c >> 2) ^ ((idx & 31) & 15)) << 2) + (c & 3);
    uint16_t tmp[8];
#pragma unroll
    for (int jj = 0; jj < 8; ++jj)
      tmp[jj] = t[(r8 + jj) * 64 + chunkbase];
    *(u32x4*)&dst[(size_t)(tc * 64 + c) * R + tr * 256 + r8] = *(const u32x4*)tmp;
  }
}

// ---------------- QKV GEMM: BM=256 x BN=256, BK=64, double-buffer (R11 winner, 65.3us) ----------------
__global__ __launch_bounds__(512, 1) void k_gemm2(
    const uint16_t* __restrict__ A0, const uint16_t* __restrict__ B0,
    const float* __restrict__ bias0, uint16_t* __restrict__ C0,
    const uint16_t* __restrict__ A1, const uint16_t* __restrict__ B1,
    const float* __restrict__ bias1, uint16_t* __restrict__ C1,
    int seg0_tiles, int N, int K) {
  __shared__ __align__(16) char lds[2 * 65536];  // per buf: A 32KB @0, B 32KB @32KB
  int bn = blockIdx.x, bm = blockIdx.y;
  const uint16_t* A; const uint16_t* B; const float* bias; uint16_t* C; int mrow;
  if (bm < seg0_tiles) { A = A0; B = B0; bias = bias0; C = C0; mrow = bm * 256; }
  else { A = A1; B = B1; bias = bias1; C = C1; mrow = (bm - seg0_tiles) * 256; }
  int tid = threadIdx.x, lane = tid & 63, w = tid >> 6;
  int g = lane >> 4, li = lane & 15;
  int wm = w >> 2, wn = w & 3;   // wm 0..1 (128-row strip), wn 0..3 (64-col strip)
  const int NKI = K / 64;

  int rowin = lane >> 3;
  int csrc = (lane & 7) ^ rowin;

  auto stage = [&](int t, char* buf) {
    int kt = t * 64;
#pragma unroll
    for (int j = 0; j < 4; ++j) {
      int r = w * 4 + j;
      int tr = r * 8 + rowin;
      async_cp16(A + (size_t)(mrow + tr) * K + kt + 8 * csrc, buf + r * 1024);
    }
#pragma unroll
    for (int j = 0; j < 4; ++j) {
      int r = w * 4 + j;
      int tr = r * 8 + rowin;
      async_cp16(B + (size_t)(bn * 256 + tr) * K + kt + 8 * csrc, buf + 32768 + r * 1024);
    }
  };

  f32x4 acc[8][4] = {};

  stage(0, lds);
  asm volatile("s_waitcnt vmcnt(0)" ::: "memory");
  __builtin_amdgcn_s_barrier();
  asm volatile("" ::: "memory");

  for (int t = 0; t < NKI; ++t) {
    const char* cur = lds + (t & 1) * 65536;
    if (t + 1 < NKI) stage(t + 1, lds + ((t + 1) & 1) * 65536);

#pragma unroll
    for (int kk = 0; kk < 2; ++kk) {
      bf16x8 af[8], bfv[4];
#pragma unroll
      for (int mi = 0; mi < 8; ++mi) {
        int row = wm * 128 + mi * 16 + li;
        int ch = (kk * 4 + g) ^ (row & 7);
        af[mi] = __builtin_bit_cast(bf16x8, *(const u32x4*)(cur + row * 128 + ch * 16));
      }
#pragma unroll
      for (int ni = 0; ni < 4; ++ni) {
        int row = wn * 64 + ni * 16 + li;
        int ch = (kk * 4 + g) ^ (row & 7);
        bfv[ni] = __builtin_bit_cast(bf16x8, *(const u32x4*)(cur + 32768 + row * 128 + ch * 16));
      }
      __builtin_amdgcn_s_setprio(1);
#pragma unroll
      for (int mi = 0; mi < 8; ++mi)
#pragma unroll
        for (int ni = 0; ni < 4; ++ni)
          acc[mi][ni] = __builtin_amdgcn_mfma_f32_16x16x32_bf16(af[mi], bfv[ni], acc[mi][ni], 0, 0, 0);
      __builtin_amdgcn_s_setprio(0);
    }

    if (t + 1 < NKI) {
      asm volatile("s_waitcnt vmcnt(0)" ::: "memory");
      __builtin_amdgcn_s_barrier();
      asm volatile("" ::: "memory");
    }
  }

#pragma unroll
  for (int mi = 0; mi < 8; ++mi) {
#pragma unroll
    for (int ni = 0; ni < 4; ++ni) {
      int col = bn * 256 + wn * 64 + ni * 16 + li;
      float bv = bias ? bias[col] : 0.0f;
#pragma unroll
      for (int i = 0; i < 4; ++i) {
        int r = mrow + wm * 128 + mi * 16 + 4 * g + i;
        C[(size_t)r * N + col] = f2bf(acc[mi][ni][i] + bv);
      }
    }
  }
}

// ---------------- out-proj GEMM: 128x128, BK=32, dbuf (R11 version) ----------------
__global__ __launch_bounds__(256, 4) void k_gemmO(
    const uint16_t* __restrict__ A0, const uint16_t* __restrict__ B0,
    const float* __restrict__ bias0, float* __restrict__ C0,
    const uint16_t* __restrict__ A1, const uint16_t* __restrict__ B1,
    const float* __restrict__ bias1, float* __restrict__ C1,
    int seg0_tiles, int N, int K) {
  __shared__ __align__(16) char lds[4 * 8192];  // A[2] @0, B[2] @16KB
  int bn = blockIdx.x, bm = blockIdx.y;
  const uint16_t* A; const uint16_t* B; const float* bias; float* C; int mrow;
  if (bm < seg0_tiles) { A = A0; B = B0; bias = bias0; C = C0; mrow = bm * 128; }
  else { A = A1; B = B1; bias = bias1; C = C1; mrow = (bm - seg0_tiles) * 128; }
  int tid = threadIdx.x, lane = tid & 63, w = tid >> 6;
  int g = lane >> 4, li = lane & 15;
  int wm = w >> 1, wn = w & 1;
  const int NKT = K / 32;

  int rowin = lane >> 2;
  int csrc = (lane & 3) ^ (rowin & 3);

  auto stage = [&](int t, int buf) {
    int kt = t * 32;
#pragma unroll
    for (int j = 0; j < 2; ++j) {
      int r = w * 2 + j;
      int tr = r * 16 + rowin;
      async_cp16(A + (size_t)(mrow + tr) * K + kt + 8 * csrc, lds + buf * 8192 + r * 1024);
    }
#pragma unroll
    for (int j = 0; j < 2; ++j) {
      int r = w * 2 + j;
      int tr = r * 16 + rowin;
      async_cp16(B + (size_t)(bn * 128 + tr) * K + kt + 8 * csrc, lds + 16384 + buf * 8192 + r * 1024);
    }
  };

  f32x4 acc[4][4] = {};
  stage(0, 0);
  asm volatile("s_waitcnt vmcnt(0)" ::: "memory");
  __builtin_amdgcn_s_barrier();
  asm volatile("" ::: "memory");

  for (int t = 0; t < NKT; ++t) {
    int cur = t & 1;
    bool pre = (t + 1 < NKT);
    if (pre) stage(t + 1, cur ^ 1);
    const char* Ac = lds + cur * 8192;
    const char* Bc = lds + 16384 + cur * 8192;

    bf16x8 af[4], bfv[4];
#pragma unroll
    for (int mi = 0; mi < 4; ++mi) {
      int row = wm * 64 + mi * 16 + li;
      af[mi] = __builtin_bit_cast(bf16x8, *(const u32x4*)(Ac + row * 64 + (g ^ (row & 3)) * 16));
    }
#pragma unroll
    for (int ni = 0; ni < 4; ++ni) {
      int row = wn * 64 + ni * 16 + li;
      bfv[ni] = __builtin_bit_cast(bf16x8, *(const u32x4*)(Bc + row * 64 + (g ^ (row & 3)) * 16));
    }
    __builtin_amdgcn_s_setprio(1);
#pragma unroll
    for (int mi = 0; mi < 4; ++mi)
#pragma unroll
      for (int ni = 0; ni < 4; ++ni)
        acc[mi][ni] = __builtin_amdgcn_mfma_f32_16x16x32_bf16(af[mi], bfv[ni], acc[mi][ni], 0, 0, 0);
    __builtin_amdgcn_s_setprio(0);

    if (pre) asm volatile("s_waitcnt vmcnt(0)" ::: "memory");
    __builtin_amdgcn_s_barrier();
    asm volatile("" ::: "memory");
  }

#pragma unroll
  for (int mi = 0; mi < 4; ++mi) {
#pragma unroll
    for (int ni = 0; ni < 4; ++ni) {
      int col = bn * 128 + wn * 64 + ni * 16 + li;
      float bv = bias[col];
#pragma unroll
      for (int i = 0; i < 4; ++i) {
        int r = mrow + wm * 64 + mi * 16 + 4 * g + i;
        C[(size_t)r * N + col] = acc[mi][ni][i] + bv;
      }
    }
  }
}

// ---------------- merged postprocess + V transpose ----------------
__global__ __launch_bounds__(256) void k_postvt(
    const uint16_t* __restrict__ qkv_img, const uint16_t* __restrict__ qkv_txt,
    const float* __restrict__ fcos, const float* __restrict__ fsin,
    const float* __restrict__ wq, const float* __restrict__ wk,
    const float* __restrict__ waq, const float* __restrict__ wak,
    uint16_t* __restrict__ Qo, uint16_t* __restrict__ Ko, uint16_t* __restrict__ VTo) {
  __shared__ uint16_t Vl[64][136];   // used by VT branch only
  if (blockIdx.x < S_ALL) {
    int s = blockIdx.x;
    const uint16_t* row = (s < S_TXT) ? qkv_txt + (size_t)s * N_QKV
                                      : qkv_img + (size_t)(s - S_TXT) * N_QKV;
    const float* wqp = (s < S_TXT) ? waq : wq;
    const float* wkp = (s < S_TXT) ? wak : wk;
    int lane = threadIdx.x & 63, w = threadIdx.x >> 6;
    int h = w * 4 + (lane >> 4);
    int d0 = (lane & 15) * 8;
    float cs[8], sn[8];
#pragma unroll
    for (int j = 0; j < 8; ++j) {
      cs[j] = fcos[s * HD + d0 + j];
      sn[j] = fsin[s * HD + d0 + j];
    }
#pragma unroll
    for (int part = 0; part < 2; ++part) {  // 0 = Q, 1 = K
      const uint16_t* src = row + part * INNER + h * HD + d0;
      u32x4 raw = *(const u32x4*)src;
      const uint16_t* rp = (const uint16_t*)&raw;
      float x[8], ss = 0.f;
#pragma unroll
      for (int j = 0; j < 8; ++j) { x[j] = bf2f(rp[j]); ss += x[j] * x[j]; }
      ss += __shfl_xor(ss, 1); ss += __shfl_xor(ss, 2);
      ss += __shfl_xor(ss, 4); ss += __shfl_xor(ss, 8);
      float rn = rsqrtf(ss * (1.0f / HD) + ATT_EPS);
      const float* wp = part ? wkp : wqp;
#pragma unroll
      for (int j = 0; j < 8; ++j) x[j] = x[j] * rn * wp[d0 + j];
      float y[8];
#pragma unroll
      for (int j = 0; j < 8; j += 2) {
        y[j]     = x[j] * cs[j] - x[j + 1] * sn[j];
        y[j + 1] = x[j + 1] * cs[j + 1] + x[j] * sn[j + 1];
      }
      float sc = part ? 1.0f : (ATT_SCALE * LOG2E);
      uint16_t ov[8];
#pragma unroll
      for (int j = 0; j < 8; ++j) ov[j] = f2bf(y[j] * sc);
      uint16_t* dst = (part ? Ko : Qo) + ((size_t)h * S_ALL + s) * HD + d0;
      *(u32x4*)dst = *(const u32x4*)ov;
    }
  } else {
    int b = blockIdx.x - S_ALL;
    int st = b % 36, h = b / 36;
    int s0 = st * 64;
    const uint16_t* base = (s0 < S_TXT) ? qkv_txt + (size_t)s0 * N_QKV
                                        : qkv_img + (size_t)(s0 - S_TXT) * N_QKV;
    base += 2 * INNER + h * HD;
    int tid = threadIdx.x;
#pragma unroll
    for (int it = 0; it < 4; ++it) {
      int idx = it * 256 + tid;
      int r = idx >> 4, c = idx & 15;
      *(u32x4*)&Vl[r][c * 8] = *(const u32x4*)(base + (size_t)r * N_QKV + c * 8);
    }
    __syncthreads();
#pragma unroll
    for (int it = 0; it < 4; ++it) {
      int idx = it * 256 + tid;
      int d = idx >> 3, sc = (idx & 7) * 8;
      uint16_t tmp[8];
#pragma unroll
      for (int j = 0; j < 8; ++j) tmp[j] = Vl[sc + j][d];
      *(u32x4*)&VTo[((size_t)h * HD + d) * S_ALL + s0 + sc] = *(const u32x4*)tmp;
    }
  }
}

// ---------------- attention (R11 winner: split-KV x4, bf16 partials, cvt_pk P-pack) ----------------
__global__ __launch_bounds__(256, 3) void k_attn(
    const uint16_t* __restrict__ Qg, const uint16_t* __restrict__ Kg,
    const uint16_t* __restrict__ VTg,
    uint16_t* __restrict__ part0, uint16_t* __restrict__ part1,
    uint16_t* __restrict__ part2, uint16_t* __restrict__ part3,
    float* __restrict__ lsumP) {
  __shared__ __align__(16) char Kt[2][8192];       // [32 key][128 d], chunk^=(row&15)
  __shared__ __align__(16) char Vt[2][8192];       // [128 d][32 s], chunk^=((row>>1)&3)
  __shared__ __align__(16) uint16_t Pl[4][32 * 40];  // per wave: [32 q][32 key + pad]

  int b0 = blockIdx.x;
  int bid = (b0 & 7) * 144 + (b0 >> 3);  // XCD-chunked: 2 heads per XCD
  int h = bid / 72, r6 = bid % 72, sp = r6 / 18, qt = r6 % 18;
  int tid = threadIdx.x, lane = tid & 63, w = tid >> 6;
  int g = lane >> 4, li = lane & 15;

  const uint16_t* Kh = Kg + (size_t)h * S_ALL * HD;
  const uint16_t* Vh = VTg + (size_t)h * HD * S_ALL;
  uint16_t* po = (sp & 2) ? ((sp & 1) ? part3 : part2) : ((sp & 1) ? part1 : part0);
  po += ((size_t)(h * QT_N + qt) * 128 + w * 32) * 128;

  int qbase = qt * 128 + w * 32;
  bf16x8 qf[2][4];
#pragma unroll
  for (int q2 = 0; q2 < 2; ++q2) {
    const uint16_t* qp = Qg + ((size_t)h * S_ALL + qbase + q2 * 16 + li) * HD;
#pragma unroll
    for (int kc = 0; kc < 4; ++kc)
      qf[q2][kc] = __builtin_bit_cast(bf16x8, *(const u32x4*)(qp + kc * 32 + g * 8));
  }
  f32x4 o[2][8] = {};
  float lsum[2] = {0.f, 0.f};

  auto stage = [&](int tk, int buf) {
#pragma unroll
    for (int j = 0; j < 2; ++j) {
      int cj = w * 128 + j * 64 + lane;
      int row = cj >> 4, c = (cj & 15) ^ (row & 15);
      async_cp16(Kh + (size_t)(tk * 32 + row) * HD + 8 * c, Kt[buf] + (w * 128 + j * 64) * 16);
    }
#pragma unroll
    for (int j = 0; j < 2; ++j) {
      int cj = w * 128 + j * 64 + lane;
      int row = cj >> 2, c = (cj & 3) ^ ((row >> 1) & 3);
      async_cp16(Vh + (size_t)row * S_ALL + tk * 32 + 8 * c, Vt[buf] + (w * 128 + j * 64) * 16);
    }
  };

  int t0 = sp * TPS;
  stage(t0, 0);
  asm volatile("s_waitcnt vmcnt(0)" ::: "memory");
  __builtin_amdgcn_s_barrier();
  asm volatile("" ::: "memory");

  for (int t = 0; t < TPS; ++t) {
    int cur = t & 1;
    if (t + 1 < TPS) stage(t0 + t + 1, cur ^ 1);
    const char* KtC = Kt[cur];
    const char* VtC = Vt[cur];

    f32x4 sc[2][2];
#pragma unroll
    for (int q2 = 0; q2 < 2; ++q2)
#pragma unroll
      for (int kb = 0; kb < 2; ++kb)
        sc[q2][kb] = (f32x4){-MBOUND, -MBOUND, -MBOUND, -MBOUND};
    __builtin_amdgcn_s_setprio(1);
#pragma unroll
    for (int kb = 0; kb < 2; ++kb)
#pragma unroll
      for (int kc = 0; kc < 4; ++kc) {
        int ch = (kc * 4 + g) ^ li;
        bf16x8 kf = __builtin_bit_cast(bf16x8,
            *(const u32x4*)(KtC + (kb * 16 + li) * 256 + ch * 16));
        sc[0][kb] = __builtin_amdgcn_mfma_f32_16x16x32_bf16(kf, qf[0][kc], sc[0][kb], 0, 0, 0);
        sc[1][kb] = __builtin_amdgcn_mfma_f32_16x16x32_bf16(kf, qf[1][kc], sc[1][kb], 0, 0, 0);
      }
    __builtin_amdgcn_s_setprio(0);

    uint16_t* Pw = &Pl[w][0];
#pragma unroll
    for (int q2 = 0; q2 < 2; ++q2)
#pragma unroll
      for (int kb = 0; kb < 2; ++kb) {
        float p0 = fexp2(sc[q2][kb][0]);
        float p1 = fexp2(sc[q2][kb][1]);
        float p2 = fexp2(sc[q2][kb][2]);
        float p3 = fexp2(sc[q2][kb][3]);
        lsum[q2] += (p0 + p1) + (p2 + p3);
        uint2 pk;
        pk.x = cvt_pk_bf16(p0, p1);
        pk.y = cvt_pk_bf16(p2, p3);
        *(uint2*)((char*)Pw + (q2 * 16 + li) * 80 + kb * 32 + g * 8) = pk;
      }

    bf16x8 pf[2];
#pragma unroll
    for (int q2 = 0; q2 < 2; ++q2)
      pf[q2] = __builtin_bit_cast(bf16x8,
          *(const u32x4*)((const char*)Pw + (q2 * 16 + li) * 80 + g * 16));
    __builtin_amdgcn_s_setprio(1);
#pragma unroll
    for (int db = 0; db < 8; ++db) {
      int vrow = db * 16 + li;
      int ch = g ^ ((vrow >> 1) & 3);
      bf16x8 vf = __builtin_bit_cast(bf16x8, *(const u32x4*)(VtC + vrow * 64 + ch * 16));
      o[0][db] = __builtin_amdgcn_mfma_f32_16x16x32_bf16(pf[0], vf, o[0][db], 0, 0, 0);
      o[1][db] = __builtin_amdgcn_mfma_f32_16x16x32_bf16(pf[1], vf, o[1][db], 0, 0, 0);
    }
    __builtin_amdgcn_s_setprio(0);

    asm volatile("s_waitcnt vmcnt(0)" ::: "memory");
    __builtin_amdgcn_s_barrier();
    asm volatile("" ::: "memory");
  }

#pragma unroll
  for (int q2 = 0; q2 < 2; ++q2) {
    float v = lsum[q2];
    v += __shfl_xor(v, 16);
    v += __shfl_xor(v, 32);
    lsum[q2] = v;
  }
  if (lane < 16) {
#pragma unroll
    for (int q2 = 0; q2 < 2; ++q2)
      lsumP[((size_t)sp * HEADS + h) * S_ALL + qbase + q2 * 16 + lane] = lsum[q2];
  }
  // bf16 partial O: row = q2*16+4g+i, col = db*16+li
#pragma unroll
  for (int q2 = 0; q2 < 2; ++q2)
#pragma unroll
    for (int db = 0; db < 8; ++db)
#pragma unroll
      for (int i = 0; i < 4; ++i)
        po[(q2 * 16 + 4 * g + i) * 128 + db * 16 + li] = f2bf(o[q2][db][i]);
}

// combine (16B vectorized): attn[q][h*128+d] = bf16(sum(parts) / sum(lsums))
__global__ __launch_bounds__(256) void k_comb(
    const uint16_t* __restrict__ p0, const uint16_t* __restrict__ p1,
    const uint16_t* __restrict__ p2, const uint16_t* __restrict__ p3,
    const float* __restrict__ lsumP, uint16_t* __restrict__ attn) {
  int q = blockIdx.x, qt = q >> 7, ql = q & 127;
  int d = threadIdx.x * 8, h = d >> 7, dl = d & 127;
  size_t off = (((size_t)h * QT_N + qt) * 128 + ql) * 128 + dl;
  u32x4 a = *(const u32x4*)&p0[off];
  u32x4 b = *(const u32x4*)&p1[off];
  u32x4 c = *(const u32x4*)&p2[off];
  u32x4 e = *(const u32x4*)&p3[off];
  const uint16_t* ap = (const uint16_t*)&a;
  const uint16_t* bp = (const uint16_t*)&b;
  const uint16_t* cp = (const uint16_t*)&c;
  const uint16_t* ep = (const uint16_t*)&e;
  float l = 0.f;
#pragma unroll
  for (int s = 0; s < 4; ++s)
    l += lsumP[((size_t)s * HEADS + h) * S_ALL + q];
  float inv = 1.0f / l;
  uint16_t ov[8];
#pragma unroll
  for (int j = 0; j < 8; ++j)
    ov[j] = f2bf((bf2f(ap[j]) + bf2f(bp[j]) + bf2f(cp[j]) + bf2f(ep[j])) * inv);
  *(u32x4*)&attn[(size_t)q * INNER + d] = *(const u32x4*)ov;
}

// ---------------- launch ----------------
extern "C" void kernel_launch(void* const* d_in, const int* in_sizes, int n_in,
                              void* d_out, int out_size, void* d_ws, size_t ws_size,
                              hipStream_t stream) {
  const float* hidden = (const float*)d_in[0];
  const float* enc    = (const float*)d_in[1];
  const float* fcos   = (const float*)d_in[2];
  const float* fsin   = (const float*)d_in[3];
  const float* Wqkv   = (const float*)d_in[4];
  const float* Wqkva  = (const float*)d_in[5];
  const float* bqkva  = (const float*)d_in[6];
  const float* nqw    = (const float*)d_in[7];
  const float* nkw    = (const float*)d_in[8];
  const float* naqw   = (const float*)d_in[9];
  const float* nakw   = (const float*)d_in[10];
  const float* Wout   = (const float*)d_in[11];
  const float* bout   = (const float*)d_in[12];
  const float* Wadd   = (const float*)d_in[13];
  const float* badd   = (const float*)d_in[14];
  float* out_img = (float*)d_out;
  float* out_enc = (float*)d_out + (size_t)S_IMG * DMODEL;

  char* ws = (char*)d_ws;
  size_t off = 0;
  auto alloc = [&](size_t bytes) {
    char* p = ws + off;
    off += (bytes + 255) & ~(size_t)255;
    return p;
  };
  uint16_t* hs_bf   = (uint16_t*)alloc((size_t)S_IMG * DMODEL * 2);
  uint16_t* enc_bf  = (uint16_t*)alloc((size_t)S_TXT * DMODEL * 2);
  char*     wqkv_base = alloc((size_t)N_QKV * DMODEL * 2 * 2);  // WqkvT + WqkvaT (reused later)
  uint16_t* WqkvT   = (uint16_t*)wqkv_base;
  uint16_t* WqkvaT  = (uint16_t*)(wqkv_base + (size_t)N_QKV * DMODEL * 2);
  uint16_t* WoutT   = (uint16_t*)alloc((size_t)DMODEL * INNER * 2);
  uint16_t* WaddT   = (uint16_t*)alloc((size_t)DMODEL * INNER * 2);
  uint16_t* qkv_img = (uint16_t*)alloc((size_t)S_IMG * N_QKV * 2);
  uint16_t* qkv_txt = (uint16_t*)alloc((size_t)S_TXT * N_QKV * 2);
  // overlay Q/K/VT/attn on the Wqkv(T) region (dead after qkv GEMM)
  uint16_t* Qb   = (uint16_t*)wqkv_base;
  uint16_t* Kb   = Qb + (size_t)HEADS * S_ALL * HD;
  uint16_t* VTb  = Kb + (size_t)HEADS * S_ALL * HD;
  uint16_t* attn = VTb + (size_t)HEADS * S_ALL * HD;
  // bf16 partials: splits 0,1 -> d_out; splits 2,3 -> dead qkv_img
  uint16_t* part0 = (uint16_t*)d_out;
  uint16_t* part1 = part0 + (size_t)S_ALL * INNER;
  uint16_t* part2 = (uint16_t*)qkv_img;
  uint16_t* part3 = part2 + (size_t)S_ALL * INNER;
  float* lsumP = (float*)enc_bf;         // dead after qkv GEMM

  k_prep<<<3200, 256, 0, stream>>>(Wqkv, WqkvT, Wqkva, WqkvaT, Wout, WoutT, Wadd, WaddT,
                                   hidden, hs_bf, S_IMG * DMODEL / 4,
                                   enc, enc_bf, S_TXT * DMODEL / 4);

  dim3 gq(N_QKV / 256, (S_TXT + S_IMG) / 256);
  k_gemm2<<<gq, 512, 0, stream>>>(enc_bf, WqkvaT, bqkva, qkv_txt,
                                  hs_bf, WqkvT, nullptr, qkv_img,
                                  1, N_QKV, DMODEL);

  k_postvt<<<S_ALL + 36 * HEADS, 256, 0, stream>>>(qkv_img, qkv_txt, fcos, fsin,
                                                   nqw, nkw, naqw, nakw, Qb, Kb, VTb);

  k_attn<<<HEADS * QT_N * 4, 256, 0, stream>>>(Qb, Kb, VTb, part0, part1, part2, part3, lsumP);
  k_comb<<<S_ALL, 256, 0, stream>>>(part0, part1, part2, part3, lsumP, attn);

  dim3 go(DMODEL / 128, S_ALL / 128);
  k_gemmO<<<go, 256, 0, stream>>>(attn, WaddT, badd, out_enc,
                                  attn + (size_t)S_TXT * INNER, WoutT, bout, out_img,
                                  2, DMODEL, DMODEL);
}

// Round 17
// 209.493 us; speedup vs baseline: 1.0152x; 1.0152x over previous
//
#include <hip/hip_runtime.h>
#include <stdint.h>

#define HEADS 16
#define HD 128
#define S_TXT 256
#define S_IMG 2048
#define S_ALL 2304
#define DMODEL 2048
#define N_QKV 6144
#define INNER 2048
#define ATT_EPS 1e-5f
#define ATT_SCALE 0.08838834764831845f
#define LOG2E 1.4426950408889634f
#define MBOUND 16.5f
#define QT_N 18      // 2304 / 128
#define TPS 18       // KV tiles (of 32) per split (4 splits)

typedef __attribute__((ext_vector_type(8))) __bf16 bf16x8;
typedef __attribute__((ext_vector_type(4))) float f32x4;
typedef __attribute__((ext_vector_type(4))) uint32_t u32x4;

__device__ __forceinline__ uint16_t f2bf(float f) {
  union { float f; uint32_t u; } v; v.f = f;
  uint32_t r = (v.u + 0x7FFF + ((v.u >> 16) & 1)) >> 16;
  return (uint16_t)r;
}
__device__ __forceinline__ float bf2f(uint16_t h) {
  union { float f; uint32_t u; } v; v.u = ((uint32_t)h) << 16;
  return v.f;
}
// packed fp32x2 -> bf16x2 (RNE), single VALU op; no builtin on gfx950
__device__ __forceinline__ uint32_t cvt_pk_bf16(float lo, float hi) {
  uint32_t r;
  asm("v_cvt_pk_bf16_f32 %0, %1, %2" : "=v"(r) : "v"(lo), "v"(hi));
  return r;
}
__device__ __forceinline__ float fexp2(float x) {
#if __has_builtin(__builtin_amdgcn_exp2f)
  return __builtin_amdgcn_exp2f(x);
#else
  return __expf(x * 0.69314718055994531f);
#endif
}

// async global->LDS, 16B per lane; lds ptr is wave-uniform base (HW adds lane*16)
__device__ __forceinline__ void async_cp16(const void* g, void* l) {
  __builtin_amdgcn_global_load_lds(
      (const __attribute__((address_space(1))) void*)g,
      (__attribute__((address_space(3))) void*)l, 16, 0, 0);
}

// ---------------- prep: 4 transposing weight converts (64x64 f32 LDS tiles, pad 65)
// + 2 straight converts, one launch (R15 measured-best version) ----------------
__global__ __launch_bounds__(256) void k_prep(
    const float* __restrict__ s0, uint16_t* __restrict__ d0,
    const float* __restrict__ s1, uint16_t* __restrict__ d1,
    const float* __restrict__ s2, uint16_t* __restrict__ d2,
    const float* __restrict__ s3, uint16_t* __restrict__ d3,
    const float* __restrict__ c0, uint16_t* __restrict__ e0, int n40,
    const float* __restrict__ c1, uint16_t* __restrict__ e1, int n41) {
  __shared__ float t[64][65];   // pad 65: store-phase reads 2-way (free)
  int b = blockIdx.x;
  if (b >= 8192) {  // straight converts
    const float* src; uint16_t* dst; int n4, bid, nb;
    if (b < 9216) { src = c0; dst = e0; n4 = n40; bid = b - 8192; nb = 1024; }
    else { src = c1; dst = e1; n4 = n41; bid = b - 9216; nb = 128; }
    int i = bid * 256 + threadIdx.x;
    int stride = nb * 256;
    for (; i < n4; i += stride) {
      float4 v = ((const float4*)src)[i];
      uint2 o;
      o.x = cvt_pk_bf16(v.x, v.y);
      o.y = cvt_pk_bf16(v.z, v.w);
      ((uint2*)dst)[i] = o;
    }
    return;
  }
  const float* src; uint16_t* dst; int R, C, tb;
  if (b < 3072)      { src = s0; dst = d0; R = DMODEL; C = N_QKV;  tb = b; }
  else if (b < 6144) { src = s1; dst = d1; R = DMODEL; C = N_QKV;  tb = b - 3072; }
  else if (b < 7168) { src = s2; dst = d2; R = INNER;  C = DMODEL; tb = b - 6144; }
  else               { src = s3; dst = d3; R = INNER;  C = DMODEL; tb = b - 7168; }
  int ntr = R >> 6;
  int tr = tb % ntr, tc = tb / ntr;
  int tid = threadIdx.x;
  int rr = tid >> 4, c4 = (tid & 15) * 4;
#pragma unroll
  for (int j = 0; j < 4; ++j) {
    int r = rr + j * 16;
    float4 v = *(const float4*)&src[(size_t)(tr * 64 + r) * C + tc * 64 + c4];
    *(float4*)&t[r][c4] = v;
  }
  __syncthreads();
  int cc = tid >> 4, r4 = (tid & 15) * 4;
#pragma unroll
  for (int j = 0; j < 4; ++j) {
    int c = cc + j * 16;
    uint2 o;
    o.x = cvt_pk_bf16(t[r4 + 0][c], t[r4 + 1][c]);
    o.y = cvt_pk_bf16(t[r4 + 2][c], t[r4 + 3][c]);
    *(uint2*)&dst[(size_t)(tc * 64 + c) * R + tr * 64 + r4] = o;
  }
}

// ---------------- QKV GEMM: BM=256 x BN=256, BK=64, double-buffer (R11 winner, 65.3us) ----------------
__global__ __launch_bounds__(512, 1) void k_gemm2(
    const uint16_t* __restrict__ A0, const uint16_t* __restrict__ B0,
    const float* __restrict__ bias0, uint16_t* __restrict__ C0,
    const uint16_t* __restrict__ A1, const uint16_t* __restrict__ B1,
    const float* __restrict__ bias1, uint16_t* __restrict__ C1,
    int seg0_tiles, int N, int K) {
  __shared__ __align__(16) char lds[2 * 65536];  // per buf: A 32KB @0, B 32KB @32KB
  int bn = blockIdx.x, bm = blockIdx.y;
  const uint16_t* A; const uint16_t* B; const float* bias; uint16_t* C; int mrow;
  if (bm < seg0_tiles) { A = A0; B = B0; bias = bias0; C = C0; mrow = bm * 256; }
  else { A = A1; B = B1; bias = bias1; C = C1; mrow = (bm - seg0_tiles) * 256; }
  int tid = threadIdx.x, lane = tid & 63, w = tid >> 6;
  int g = lane >> 4, li = lane & 15;
  int wm = w >> 2, wn = w & 3;   // wm 0..1 (128-row strip), wn 0..3 (64-col strip)
  const int NKI = K / 64;

  int rowin = lane >> 3;
  int csrc = (lane & 7) ^ rowin;

  auto stage = [&](int t, char* buf) {
    int kt = t * 64;
#pragma unroll
    for (int j = 0; j < 4; ++j) {
      int r = w * 4 + j;
      int tr = r * 8 + rowin;
      async_cp16(A + (size_t)(mrow + tr) * K + kt + 8 * csrc, buf + r * 1024);
    }
#pragma unroll
    for (int j = 0; j < 4; ++j) {
      int r = w * 4 + j;
      int tr = r * 8 + rowin;
      async_cp16(B + (size_t)(bn * 256 + tr) * K + kt + 8 * csrc, buf + 32768 + r * 1024);
    }
  };

  f32x4 acc[8][4] = {};

  stage(0, lds);
  asm volatile("s_waitcnt vmcnt(0)" ::: "memory");
  __builtin_amdgcn_s_barrier();
  asm volatile("" ::: "memory");

  for (int t = 0; t < NKI; ++t) {
    const char* cur = lds + (t & 1) * 65536;
    if (t + 1 < NKI) stage(t + 1, lds + ((t + 1) & 1) * 65536);

#pragma unroll
    for (int kk = 0; kk < 2; ++kk) {
      bf16x8 af[8], bfv[4];
#pragma unroll
      for (int mi = 0; mi < 8; ++mi) {
        int row = wm * 128 + mi * 16 + li;
        int ch = (kk * 4 + g) ^ (row & 7);
        af[mi] = __builtin_bit_cast(bf16x8, *(const u32x4*)(cur + row * 128 + ch * 16));
      }
#pragma unroll
      for (int ni = 0; ni < 4; ++ni) {
        int row = wn * 64 + ni * 16 + li;
        int ch = (kk * 4 + g) ^ (row & 7);
        bfv[ni] = __builtin_bit_cast(bf16x8, *(const u32x4*)(cur + 32768 + row * 128 + ch * 16));
      }
      __builtin_amdgcn_s_setprio(1);
#pragma unroll
      for (int mi = 0; mi < 8; ++mi)
#pragma unroll
        for (int ni = 0; ni < 4; ++ni)
          acc[mi][ni] = __builtin_amdgcn_mfma_f32_16x16x32_bf16(af[mi], bfv[ni], acc[mi][ni], 0, 0, 0);
      __builtin_amdgcn_s_setprio(0);
    }

    if (t + 1 < NKI) {
      asm volatile("s_waitcnt vmcnt(0)" ::: "memory");
      __builtin_amdgcn_s_barrier();
      asm volatile("" ::: "memory");
    }
  }

#pragma unroll
  for (int mi = 0; mi < 8; ++mi) {
#pragma unroll
    for (int ni = 0; ni < 4; ++ni) {
      int col = bn * 256 + wn * 64 + ni * 16 + li;
      float bv = bias ? bias[col] : 0.0f;
#pragma unroll
      for (int i = 0; i < 4; ++i) {
        int r = mrow + wm * 128 + mi * 16 + 4 * g + i;
        C[(size_t)r * N + col] = f2bf(acc[mi][ni][i] + bv);
      }
    }
  }
}

// ---------------- out-proj GEMM: 128x128, BK=32, dbuf (R11 version) ----------------
__global__ __launch_bounds__(256, 4) void k_gemmO(
    const uint16_t* __restrict__ A0, const uint16_t* __restrict__ B0,
    const float* __restrict__ bias0, float* __restrict__ C0,
    const uint16_t* __restrict__ A1, const uint16_t* __restrict__ B1,
    const float* __restrict__ bias1, float* __restrict__ C1,
    int seg0_tiles, int N, int K) {
  __shared__ __align__(16) char lds[4 * 8192];  // A[2] @0, B[2] @16KB
  int bn = blockIdx.x, bm = blockIdx.y;
  const uint16_t* A; const uint16_t* B; const float* bias; float* C; int mrow;
  if (bm < seg0_tiles) { A = A0; B = B0; bias = bias0; C = C0; mrow = bm * 128; }
  else { A = A1; B = B1; bias = bias1; C = C1; mrow = (bm - seg0_tiles) * 128; }
  int tid = threadIdx.x, lane = tid & 63, w = tid >> 6;
  int g = lane >> 4, li = lane & 15;
  int wm = w >> 1, wn = w & 1;
  const int NKT = K / 32;

  int rowin = lane >> 2;
  int csrc = (lane & 3) ^ (rowin & 3);

  auto stage = [&](int t, int buf) {
    int kt = t * 32;
#pragma unroll
    for (int j = 0; j < 2; ++j) {
      int r = w * 2 + j;
      int tr = r * 16 + rowin;
      async_cp16(A + (size_t)(mrow + tr) * K + kt + 8 * csrc, lds + buf * 8192 + r * 1024);
    }
#pragma unroll
    for (int j = 0; j < 2; ++j) {
      int r = w * 2 + j;
      int tr = r * 16 + rowin;
      async_cp16(B + (size_t)(bn * 128 + tr) * K + kt + 8 * csrc, lds + 16384 + buf * 8192 + r * 1024);
    }
  };

  f32x4 acc[4][4] = {};
  stage(0, 0);
  asm volatile("s_waitcnt vmcnt(0)" ::: "memory");
  __builtin_amdgcn_s_barrier();
  asm volatile("" ::: "memory");

  for (int t = 0; t < NKT; ++t) {
    int cur = t & 1;
    bool pre = (t + 1 < NKT);
    if (pre) stage(t + 1, cur ^ 1);
    const char* Ac = lds + cur * 8192;
    const char* Bc = lds + 16384 + cur * 8192;

    bf16x8 af[4], bfv[4];
#pragma unroll
    for (int mi = 0; mi < 4; ++mi) {
      int row = wm * 64 + mi * 16 + li;
      af[mi] = __builtin_bit_cast(bf16x8, *(const u32x4*)(Ac + row * 64 + (g ^ (row & 3)) * 16));
    }
#pragma unroll
    for (int ni = 0; ni < 4; ++ni) {
      int row = wn * 64 + ni * 16 + li;
      bfv[ni] = __builtin_bit_cast(bf16x8, *(const u32x4*)(Bc + row * 64 + (g ^ (row & 3)) * 16));
    }
    __builtin_amdgcn_s_setprio(1);
#pragma unroll
    for (int mi = 0; mi < 4; ++mi)
#pragma unroll
      for (int ni = 0; ni < 4; ++ni)
        acc[mi][ni] = __builtin_amdgcn_mfma_f32_16x16x32_bf16(af[mi], bfv[ni], acc[mi][ni], 0, 0, 0);
    __builtin_amdgcn_s_setprio(0);

    if (pre) asm volatile("s_waitcnt vmcnt(0)" ::: "memory");
    __builtin_amdgcn_s_barrier();
    asm volatile("" ::: "memory");
  }

#pragma unroll
  for (int mi = 0; mi < 4; ++mi) {
#pragma unroll
    for (int ni = 0; ni < 4; ++ni) {
      int col = bn * 128 + wn * 64 + ni * 16 + li;
      float bv = bias[col];
#pragma unroll
      for (int i = 0; i < 4; ++i) {
        int r = mrow + wm * 64 + mi * 16 + 4 * g + i;
        C[(size_t)r * N + col] = acc[mi][ni][i] + bv;
      }
    }
  }
}

// ---------------- merged postprocess + V transpose ----------------
__global__ __launch_bounds__(256) void k_postvt(
    const uint16_t* __restrict__ qkv_img, const uint16_t* __restrict__ qkv_txt,
    const float* __restrict__ fcos, const float* __restrict__ fsin,
    const float* __restrict__ wq, const float* __restrict__ wk,
    const float* __restrict__ waq, const float* __restrict__ wak,
    uint16_t* __restrict__ Qo, uint16_t* __restrict__ Ko, uint16_t* __restrict__ VTo) {
  __shared__ uint16_t Vl[64][136];   // used by VT branch only
  if (blockIdx.x < S_ALL) {
    int s = blockIdx.x;
    const uint16_t* row = (s < S_TXT) ? qkv_txt + (size_t)s * N_QKV
                                      : qkv_img + (size_t)(s - S_TXT) * N_QKV;
    const float* wqp = (s < S_TXT) ? waq : wq;
    const float* wkp = (s < S_TXT) ? wak : wk;
    int lane = threadIdx.x & 63, w = threadIdx.x >> 6;
    int h = w * 4 + (lane >> 4);
    int d0 = (lane & 15) * 8;
    float cs[8], sn[8];
#pragma unroll
    for (int j = 0; j < 8; ++j) {
      cs[j] = fcos[s * HD + d0 + j];
      sn[j] = fsin[s * HD + d0 + j];
    }
#pragma unroll
    for (int part = 0; part < 2; ++part) {  // 0 = Q, 1 = K
      const uint16_t* src = row + part * INNER + h * HD + d0;
      u32x4 raw = *(const u32x4*)src;
      const uint16_t* rp = (const uint16_t*)&raw;
      float x[8], ss = 0.f;
#pragma unroll
      for (int j = 0; j < 8; ++j) { x[j] = bf2f(rp[j]); ss += x[j] * x[j]; }
      ss += __shfl_xor(ss, 1); ss += __shfl_xor(ss, 2);
      ss += __shfl_xor(ss, 4); ss += __shfl_xor(ss, 8);
      float rn = rsqrtf(ss * (1.0f / HD) + ATT_EPS);
      const float* wp = part ? wkp : wqp;
#pragma unroll
      for (int j = 0; j < 8; ++j) x[j] = x[j] * rn * wp[d0 + j];
      float y[8];
#pragma unroll
      for (int j = 0; j < 8; j += 2) {
        y[j]     = x[j] * cs[j] - x[j + 1] * sn[j];
        y[j + 1] = x[j + 1] * cs[j + 1] + x[j] * sn[j + 1];
      }
      float sc = part ? 1.0f : (ATT_SCALE * LOG2E);
      uint16_t ov[8];
#pragma unroll
      for (int j = 0; j < 8; ++j) ov[j] = f2bf(y[j] * sc);
      uint16_t* dst = (part ? Ko : Qo) + ((size_t)h * S_ALL + s) * HD + d0;
      *(u32x4*)dst = *(const u32x4*)ov;
    }
  } else {
    int b = blockIdx.x - S_ALL;
    int st = b % 36, h = b / 36;
    int s0 = st * 64;
    const uint16_t* base = (s0 < S_TXT) ? qkv_txt + (size_t)s0 * N_QKV
                                        : qkv_img + (size_t)(s0 - S_TXT) * N_QKV;
    base += 2 * INNER + h * HD;
    int tid = threadIdx.x;
#pragma unroll
    for (int it = 0; it < 4; ++it) {
      int idx = it * 256 + tid;
      int r = idx >> 4, c = idx & 15;
      *(u32x4*)&Vl[r][c * 8] = *(const u32x4*)(base + (size_t)r * N_QKV + c * 8);
    }
    __syncthreads();
#pragma unroll
    for (int it = 0; it < 4; ++it) {
      int idx = it * 256 + tid;
      int d = idx >> 3, sc = (idx & 7) * 8;
      uint16_t tmp[8];
#pragma unroll
      for (int j = 0; j < 8; ++j) tmp[j] = Vl[sc + j][d];
      *(u32x4*)&VTo[((size_t)h * HD + d) * S_ALL + s0 + sc] = *(const u32x4*)tmp;
    }
  }
}

// ---------------- attention (R11 winner: split-KV x4, bf16 partials, cvt_pk P-pack) ----------------
__global__ __launch_bounds__(256, 3) void k_attn(
    const uint16_t* __restrict__ Qg, const uint16_t* __restrict__ Kg,
    const uint16_t* __restrict__ VTg,
    uint16_t* __restrict__ part0, uint16_t* __restrict__ part1,
    uint16_t* __restrict__ part2, uint16_t* __restrict__ part3,
    float* __restrict__ lsumP) {
  __shared__ __align__(16) char Kt[2][8192];       // [32 key][128 d], chunk^=(row&15)
  __shared__ __align__(16) char Vt[2][8192];       // [128 d][32 s], chunk^=((row>>1)&3)
  __shared__ __align__(16) uint16_t Pl[4][32 * 40];  // per wave: [32 q][32 key + pad]

  int b0 = blockIdx.x;
  int bid = (b0 & 7) * 144 + (b0 >> 3);  // XCD-chunked: 2 heads per XCD
  int h = bid / 72, r6 = bid % 72, sp = r6 / 18, qt = r6 % 18;
  int tid = threadIdx.x, lane = tid & 63, w = tid >> 6;
  int g = lane >> 4, li = lane & 15;

  const uint16_t* Kh = Kg + (size_t)h * S_ALL * HD;
  const uint16_t* Vh = VTg + (size_t)h * HD * S_ALL;
  uint16_t* po = (sp & 2) ? ((sp & 1) ? part3 : part2) : ((sp & 1) ? part1 : part0);
  po += ((size_t)(h * QT_N + qt) * 128 + w * 32) * 128;

  int qbase = qt * 128 + w * 32;
  bf16x8 qf[2][4];
#pragma unroll
  for (int q2 = 0; q2 < 2; ++q2) {
    const uint16_t* qp = Qg + ((size_t)h * S_ALL + qbase + q2 * 16 + li) * HD;
#pragma unroll
    for (int kc = 0; kc < 4; ++kc)
      qf[q2][kc] = __builtin_bit_cast(bf16x8, *(const u32x4*)(qp + kc * 32 + g * 8));
  }
  f32x4 o[2][8] = {};
  float lsum[2] = {0.f, 0.f};

  auto stage = [&](int tk, int buf) {
#pragma unroll
    for (int j = 0; j < 2; ++j) {
      int cj = w * 128 + j * 64 + lane;
      int row = cj >> 4, c = (cj & 15) ^ (row & 15);
      async_cp16(Kh + (size_t)(tk * 32 + row) * HD + 8 * c, Kt[buf] + (w * 128 + j * 64) * 16);
    }
#pragma unroll
    for (int j = 0; j < 2; ++j) {
      int cj = w * 128 + j * 64 + lane;
      int row = cj >> 2, c = (cj & 3) ^ ((row >> 1) & 3);
      async_cp16(Vh + (size_t)row * S_ALL + tk * 32 + 8 * c, Vt[buf] + (w * 128 + j * 64) * 16);
    }
  };

  int t0 = sp * TPS;
  stage(t0, 0);
  asm volatile("s_waitcnt vmcnt(0)" ::: "memory");
  __builtin_amdgcn_s_barrier();
  asm volatile("" ::: "memory");

  for (int t = 0; t < TPS; ++t) {
    int cur = t & 1;
    if (t + 1 < TPS) stage(t0 + t + 1, cur ^ 1);
    const char* KtC = Kt[cur];
    const char* VtC = Vt[cur];

    f32x4 sc[2][2];
#pragma unroll
    for (int q2 = 0; q2 < 2; ++q2)
#pragma unroll
      for (int kb = 0; kb < 2; ++kb)
        sc[q2][kb] = (f32x4){-MBOUND, -MBOUND, -MBOUND, -MBOUND};
    __builtin_amdgcn_s_setprio(1);
#pragma unroll
    for (int kb = 0; kb < 2; ++kb)
#pragma unroll
      for (int kc = 0; kc < 4; ++kc) {
        int ch = (kc * 4 + g) ^ li;
        bf16x8 kf = __builtin_bit_cast(bf16x8,
            *(const u32x4*)(KtC + (kb * 16 + li) * 256 + ch * 16));
        sc[0][kb] = __builtin_amdgcn_mfma_f32_16x16x32_bf16(kf, qf[0][kc], sc[0][kb], 0, 0, 0);
        sc[1][kb] = __builtin_amdgcn_mfma_f32_16x16x32_bf16(kf, qf[1][kc], sc[1][kb], 0, 0, 0);
      }
    __builtin_amdgcn_s_setprio(0);

    uint16_t* Pw = &Pl[w][0];
#pragma unroll
    for (int q2 = 0; q2 < 2; ++q2)
#pragma unroll
      for (int kb = 0; kb < 2; ++kb) {
        float p0 = fexp2(sc[q2][kb][0]);
        float p1 = fexp2(sc[q2][kb][1]);
        float p2 = fexp2(sc[q2][kb][2]);
        float p3 = fexp2(sc[q2][kb][3]);
        lsum[q2] += (p0 + p1) + (p2 + p3);
        uint2 pk;
        pk.x = cvt_pk_bf16(p0, p1);
        pk.y = cvt_pk_bf16(p2, p3);
        *(uint2*)((char*)Pw + (q2 * 16 + li) * 80 + kb * 32 + g * 8) = pk;
      }

    bf16x8 pf[2];
#pragma unroll
    for (int q2 = 0; q2 < 2; ++q2)
      pf[q2] = __builtin_bit_cast(bf16x8,
          *(const u32x4*)((const char*)Pw + (q2 * 16 + li) * 80 + g * 16));
    __builtin_amdgcn_s_setprio(1);
#pragma unroll
    for (int db = 0; db < 8; ++db) {
      int vrow = db * 16 + li;
      int ch = g ^ ((vrow >> 1) & 3);
      bf16x8 vf = __builtin_bit_cast(bf16x8, *(const u32x4*)(VtC + vrow * 64 + ch * 16));
      o[0][db] = __builtin_amdgcn_mfma_f32_16x16x32_bf16(pf[0], vf, o[0][db], 0, 0, 0);
      o[1][db] = __builtin_amdgcn_mfma_f32_16x16x32_bf16(pf[1], vf, o[1][db], 0, 0, 0);
    }
    __builtin_amdgcn_s_setprio(0);

    asm volatile("s_waitcnt vmcnt(0)" ::: "memory");
    __builtin_amdgcn_s_barrier();
    asm volatile("" ::: "memory");
  }

#pragma unroll
  for (int q2 = 0; q2 < 2; ++q2) {
    float v = lsum[q2];
    v += __shfl_xor(v, 16);
    v += __shfl_xor(v, 32);
    lsum[q2] = v;
  }
  if (lane < 16) {
#pragma unroll
    for (int q2 = 0; q2 < 2; ++q2)
      lsumP[((size_t)sp * HEADS + h) * S_ALL + qbase + q2 * 16 + lane] = lsum[q2];
  }
  // bf16 partial O: row = q2*16+4g+i, col = db*16+li
#pragma unroll
  for (int q2 = 0; q2 < 2; ++q2)
#pragma unroll
    for (int db = 0; db < 8; ++db)
#pragma unroll
      for (int i = 0; i < 4; ++i)
        po[(q2 * 16 + 4 * g + i) * 128 + db * 16 + li] = f2bf(o[q2][db][i]);
}

// combine (16B vectorized): attn[q][h*128+d] = bf16(sum(parts) / sum(lsums))
__global__ __launch_bounds__(256) void k_comb(
    const uint16_t* __restrict__ p0, const uint16_t* __restrict__ p1,
    const uint16_t* __restrict__ p2, const uint16_t* __restrict__ p3,
    const float* __restrict__ lsumP, uint16_t* __restrict__ attn) {
  int q = blockIdx.x, qt = q >> 7, ql = q & 127;
  int d = threadIdx.x * 8, h = d >> 7, dl = d & 127;
  size_t off = (((size_t)h * QT_N + qt) * 128 + ql) * 128 + dl;
  u32x4 a = *(const u32x4*)&p0[off];
  u32x4 b = *(const u32x4*)&p1[off];
  u32x4 c = *(const u32x4*)&p2[off];
  u32x4 e = *(const u32x4*)&p3[off];
  const uint16_t* ap = (const uint16_t*)&a;
  const uint16_t* bp = (const uint16_t*)&b;
  const uint16_t* cp = (const uint16_t*)&c;
  const uint16_t* ep = (const uint16_t*)&e;
  float l = 0.f;
#pragma unroll
  for (int s = 0; s < 4; ++s)
    l += lsumP[((size_t)s * HEADS + h) * S_ALL + q];
  float inv = 1.0f / l;
  uint16_t ov[8];
#pragma unroll
  for (int j = 0; j < 8; ++j)
    ov[j] = f2bf((bf2f(ap[j]) + bf2f(bp[j]) + bf2f(cp[j]) + bf2f(ep[j])) * inv);
  *(u32x4*)&attn[(size_t)q * INNER + d] = *(const u32x4*)ov;
}

// ---------------- launch ----------------
extern "C" void kernel_launch(void* const* d_in, const int* in_sizes, int n_in,
                              void* d_out, int out_size, void* d_ws, size_t ws_size,
                              hipStream_t stream) {
  const float* hidden = (const float*)d_in[0];
  const float* enc    = (const float*)d_in[1];
  const float* fcos   = (const float*)d_in[2];
  const float* fsin   = (const float*)d_in[3];
  const float* Wqkv   = (const float*)d_in[4];
  const float* Wqkva  = (const float*)d_in[5];
  const float* bqkva  = (const float*)d_in[6];
  const float* nqw    = (const float*)d_in[7];
  const float* nkw    = (const float*)d_in[8];
  const float* naqw   = (const float*)d_in[9];
  const float* nakw   = (const float*)d_in[10];
  const float* Wout   = (const float*)d_in[11];
  const float* bout   = (const float*)d_in[12];
  const float* Wadd   = (const float*)d_in[13];
  const float* badd   = (const float*)d_in[14];
  float* out_img = (float*)d_out;
  float* out_enc = (float*)d_out + (size_t)S_IMG * DMODEL;

  char* ws = (char*)d_ws;
  size_t off = 0;
  auto alloc = [&](size_t bytes) {
    char* p = ws + off;
    off += (bytes + 255) & ~(size_t)255;
    return p;
  };
  uint16_t* hs_bf   = (uint16_t*)alloc((size_t)S_IMG * DMODEL * 2);
  uint16_t* enc_bf  = (uint16_t*)alloc((size_t)S_TXT * DMODEL * 2);
  char*     wqkv_base = alloc((size_t)N_QKV * DMODEL * 2 * 2);  // WqkvT + WqkvaT (reused later)
  uint16_t* WqkvT   = (uint16_t*)wqkv_base;
  uint16_t* WqkvaT  = (uint16_t*)(wqkv_base + (size_t)N_QKV * DMODEL * 2);
  uint16_t* WoutT   = (uint16_t*)alloc((size_t)DMODEL * INNER * 2);
  uint16_t* WaddT   = (uint16_t*)alloc((size_t)DMODEL * INNER * 2);
  uint16_t* qkv_img = (uint16_t*)alloc((size_t)S_IMG * N_QKV * 2);
  uint16_t* qkv_txt = (uint16_t*)alloc((size_t)S_TXT * N_QKV * 2);
  // overlay Q/K/VT/attn on the Wqkv(T) region (dead after qkv GEMM)
  uint16_t* Qb   = (uint16_t*)wqkv_base;
  uint16_t* Kb   = Qb + (size_t)HEADS * S_ALL * HD;
  uint16_t* VTb  = Kb + (size_t)HEADS * S_ALL * HD;
  uint16_t* attn = VTb + (size_t)HEADS * S_ALL * HD;
  // bf16 partials: splits 0,1 -> d_out; splits 2,3 -> dead qkv_img
  uint16_t* part0 = (uint16_t*)d_out;
  uint16_t* part1 = part0 + (size_t)S_ALL * INNER;
  uint16_t* part2 = (uint16_t*)qkv_img;
  uint16_t* part3 = part2 + (size_t)S_ALL * INNER;
  float* lsumP = (float*)enc_bf;         // dead after qkv GEMM

  k_prep<<<9344, 256, 0, stream>>>(Wqkv, WqkvT, Wqkva, WqkvaT, Wout, WoutT, Wadd, WaddT,
                                   hidden, hs_bf, S_IMG * DMODEL / 4,
                                   enc, enc_bf, S_TXT * DMODEL / 4);

  dim3 gq(N_QKV / 256, (S_TXT + S_IMG) / 256);
  k_gemm2<<<gq, 512, 0, stream>>>(enc_bf, WqkvaT, bqkva, qkv_txt,
                                  hs_bf, WqkvT, nullptr, qkv_img,
                                  1, N_QKV, DMODEL);

  k_postvt<<<S_ALL + 36 * HEADS, 256, 0, stream>>>(qkv_img, qkv_txt, fcos, fsin,
                                                   nqw, nkw, naqw, nakw, Qb, Kb, VTb);

  k_attn<<<HEADS * QT_N * 4, 256, 0, stream>>>(Qb, Kb, VTb, part0, part1, part2, part3, lsumP);
  k_comb<<<S_ALL, 256, 0, stream>>>(part0, part1, part2, part3, lsumP, attn);

  dim3 go(DMODEL / 128, S_ALL / 128);
  k_gemmO<<<go, 256, 0, stream>>>(attn, WaddT, badd, out_enc,
                                  attn + (size_t)S_TXT * INNER, WoutT, bout, out_img,
                                  2, DMODEL, DMODEL);
}

// Round 18
// 209.461 us; speedup vs baseline: 1.0153x; 1.0002x over previous
//
#include <hip/hip_runtime.h>
#include <stdint.h>

#define HEADS 16
#define HD 128
#define S_TXT 256
#define S_IMG 2048
#define S_ALL 2304
#define DMODEL 2048
#define N_QKV 6144
#define INNER 2048
#define ATT_EPS 1e-5f
#define ATT_SCALE 0.08838834764831845f
#define LOG2E 1.4426950408889634f
#define MBOUND 16.5f
#define QT_N 18      // 2304 / 128
#define TPS 18       // KV tiles (of 32) per split (4 splits)

typedef __attribute__((ext_vector_type(8))) __bf16 bf16x8;
typedef __attribute__((ext_vector_type(4))) float f32x4;
typedef __attribute__((ext_vector_type(4))) uint32_t u32x4;

__device__ __forceinline__ uint16_t f2bf(float f) {
  union { float f; uint32_t u; } v; v.f = f;
  uint32_t r = (v.u + 0x7FFF + ((v.u >> 16) & 1)) >> 16;
  return (uint16_t)r;
}
__device__ __forceinline__ float bf2f(uint16_t h) {
  union { float f; uint32_t u; } v; v.u = ((uint32_t)h) << 16;
  return v.f;
}
// packed fp32x2 -> bf16x2 (RNE), single VALU op; no builtin on gfx950
__device__ __forceinline__ uint32_t cvt_pk_bf16(float lo, float hi) {
  uint32_t r;
  asm("v_cvt_pk_bf16_f32 %0, %1, %2" : "=v"(r) : "v"(lo), "v"(hi));
  return r;
}
__device__ __forceinline__ float fexp2(float x) {
#if __has_builtin(__builtin_amdgcn_exp2f)
  return __builtin_amdgcn_exp2f(x);
#else
  return __expf(x * 0.69314718055994531f);
#endif
}

// async global->LDS, 16B per lane; lds ptr is wave-uniform base (HW adds lane*16)
__device__ __forceinline__ void async_cp16(const void* g, void* l) {
  __builtin_amdgcn_global_load_lds(
      (const __attribute__((address_space(1))) void*)g,
      (__attribute__((address_space(3))) void*)l, 16, 0, 0);
}

// ---------------- prep: 4 transposing weight converts (64x64 f32 LDS tiles, pad 65)
// + 2 straight converts, one launch (R15 measured-best version) ----------------
__global__ __launch_bounds__(256) void k_prep(
    const float* __restrict__ s0, uint16_t* __restrict__ d0,
    const float* __restrict__ s1, uint16_t* __restrict__ d1,
    const float* __restrict__ s2, uint16_t* __restrict__ d2,
    const float* __restrict__ s3, uint16_t* __restrict__ d3,
    const float* __restrict__ c0, uint16_t* __restrict__ e0, int n40,
    const float* __restrict__ c1, uint16_t* __restrict__ e1, int n41) {
  __shared__ float t[64][65];   // pad 65: store-phase reads 2-way (free)
  int b = blockIdx.x;
  if (b >= 8192) {  // straight converts
    const float* src; uint16_t* dst; int n4, bid, nb;
    if (b < 9216) { src = c0; dst = e0; n4 = n40; bid = b - 8192; nb = 1024; }
    else { src = c1; dst = e1; n4 = n41; bid = b - 9216; nb = 128; }
    int i = bid * 256 + threadIdx.x;
    int stride = nb * 256;
    for (; i < n4; i += stride) {
      float4 v = ((const float4*)src)[i];
      uint2 o;
      o.x = cvt_pk_bf16(v.x, v.y);
      o.y = cvt_pk_bf16(v.z, v.w);
      ((uint2*)dst)[i] = o;
    }
    return;
  }
  const float* src; uint16_t* dst; int R, C, tb;
  if (b < 3072)      { src = s0; dst = d0; R = DMODEL; C = N_QKV;  tb = b; }
  else if (b < 6144) { src = s1; dst = d1; R = DMODEL; C = N_QKV;  tb = b - 3072; }
  else if (b < 7168) { src = s2; dst = d2; R = INNER;  C = DMODEL; tb = b - 6144; }
  else               { src = s3; dst = d3; R = INNER;  C = DMODEL; tb = b - 7168; }
  int ntr = R >> 6;
  int tr = tb % ntr, tc = tb / ntr;
  int tid = threadIdx.x;
  int rr = tid >> 4, c4 = (tid & 15) * 4;
#pragma unroll
  for (int j = 0; j < 4; ++j) {
    int r = rr + j * 16;
    float4 v = *(const float4*)&src[(size_t)(tr * 64 + r) * C + tc * 64 + c4];
    *(float4*)&t[r][c4] = v;
  }
  __syncthreads();
  int cc = tid >> 4, r4 = (tid & 15) * 4;
#pragma unroll
  for (int j = 0; j < 4; ++j) {
    int c = cc + j * 16;
    uint2 o;
    o.x = cvt_pk_bf16(t[r4 + 0][c], t[r4 + 1][c]);
    o.y = cvt_pk_bf16(t[r4 + 2][c], t[r4 + 3][c]);
    *(uint2*)&dst[(size_t)(tc * 64 + c) * R + tr * 64 + r4] = o;
  }
}

// ---------------- QKV GEMM: BM=256 x BN=256, BK=64, double-buffer (R11 winner, 65.3us) ----------------
__global__ __launch_bounds__(512, 1) void k_gemm2(
    const uint16_t* __restrict__ A0, const uint16_t* __restrict__ B0,
    const float* __restrict__ bias0, uint16_t* __restrict__ C0,
    const uint16_t* __restrict__ A1, const uint16_t* __restrict__ B1,
    const float* __restrict__ bias1, uint16_t* __restrict__ C1,
    int seg0_tiles, int N, int K) {
  __shared__ __align__(16) char lds[2 * 65536];  // per buf: A 32KB @0, B 32KB @32KB
  int bn = blockIdx.x, bm = blockIdx.y;
  const uint16_t* A; const uint16_t* B; const float* bias; uint16_t* C; int mrow;
  if (bm < seg0_tiles) { A = A0; B = B0; bias = bias0; C = C0; mrow = bm * 256; }
  else { A = A1; B = B1; bias = bias1; C = C1; mrow = (bm - seg0_tiles) * 256; }
  int tid = threadIdx.x, lane = tid & 63, w = tid >> 6;
  int g = lane >> 4, li = lane & 15;
  int wm = w >> 2, wn = w & 3;   // wm 0..1 (128-row strip), wn 0..3 (64-col strip)
  const int NKI = K / 64;

  int rowin = lane >> 3;
  int csrc = (lane & 7) ^ rowin;

  auto stage = [&](int t, char* buf) {
    int kt = t * 64;
#pragma unroll
    for (int j = 0; j < 4; ++j) {
      int r = w * 4 + j;
      int tr = r * 8 + rowin;
      async_cp16(A + (size_t)(mrow + tr) * K + kt + 8 * csrc, buf + r * 1024);
    }
#pragma unroll
    for (int j = 0; j < 4; ++j) {
      int r = w * 4 + j;
      int tr = r * 8 + rowin;
      async_cp16(B + (size_t)(bn * 256 + tr) * K + kt + 8 * csrc, buf + 32768 + r * 1024);
    }
  };

  f32x4 acc[8][4] = {};

  stage(0, lds);
  asm volatile("s_waitcnt vmcnt(0)" ::: "memory");
  __builtin_amdgcn_s_barrier();
  asm volatile("" ::: "memory");

  for (int t = 0; t < NKI; ++t) {
    const char* cur = lds + (t & 1) * 65536;
    if (t + 1 < NKI) stage(t + 1, lds + ((t + 1) & 1) * 65536);

#pragma unroll
    for (int kk = 0; kk < 2; ++kk) {
      bf16x8 af[8], bfv[4];
#pragma unroll
      for (int mi = 0; mi < 8; ++mi) {
        int row = wm * 128 + mi * 16 + li;
        int ch = (kk * 4 + g) ^ (row & 7);
        af[mi] = __builtin_bit_cast(bf16x8, *(const u32x4*)(cur + row * 128 + ch * 16));
      }
#pragma unroll
      for (int ni = 0; ni < 4; ++ni) {
        int row = wn * 64 + ni * 16 + li;
        int ch = (kk * 4 + g) ^ (row & 7);
        bfv[ni] = __builtin_bit_cast(bf16x8, *(const u32x4*)(cur + 32768 + row * 128 + ch * 16));
      }
      __builtin_amdgcn_s_setprio(1);
#pragma unroll
      for (int mi = 0; mi < 8; ++mi)
#pragma unroll
        for (int ni = 0; ni < 4; ++ni)
          acc[mi][ni] = __builtin_amdgcn_mfma_f32_16x16x32_bf16(af[mi], bfv[ni], acc[mi][ni], 0, 0, 0);
      __builtin_amdgcn_s_setprio(0);
    }

    if (t + 1 < NKI) {
      asm volatile("s_waitcnt vmcnt(0)" ::: "memory");
      __builtin_amdgcn_s_barrier();
      asm volatile("" ::: "memory");
    }
  }

#pragma unroll
  for (int mi = 0; mi < 8; ++mi) {
#pragma unroll
    for (int ni = 0; ni < 4; ++ni) {
      int col = bn * 256 + wn * 64 + ni * 16 + li;
      float bv = bias ? bias[col] : 0.0f;
#pragma unroll
      for (int i = 0; i < 4; ++i) {
        int r = mrow + wm * 128 + mi * 16 + 4 * g + i;
        C[(size_t)r * N + col] = f2bf(acc[mi][ni][i] + bv);
      }
    }
  }
}

// ---------------- out-proj GEMM: 128x128, BK=32, dbuf (R11 version) ----------------
__global__ __launch_bounds__(256, 4) void k_gemmO(
    const uint16_t* __restrict__ A0, const uint16_t* __restrict__ B0,
    const float* __restrict__ bias0, float* __restrict__ C0,
    const uint16_t* __restrict__ A1, const uint16_t* __restrict__ B1,
    const float* __restrict__ bias1, float* __restrict__ C1,
    int seg0_tiles, int N, int K) {
  __shared__ __align__(16) char lds[4 * 8192];  // A[2] @0, B[2] @16KB
  int bn = blockIdx.x, bm = blockIdx.y;
  const uint16_t* A; const uint16_t* B; const float* bias; float* C; int mrow;
  if (bm < seg0_tiles) { A = A0; B = B0; bias = bias0; C = C0; mrow = bm * 128; }
  else { A = A1; B = B1; bias = bias1; C = C1; mrow = (bm - seg0_tiles) * 128; }
  int tid = threadIdx.x, lane = tid & 63, w = tid >> 6;
  int g = lane >> 4, li = lane & 15;
  int wm = w >> 1, wn = w & 1;
  const int NKT = K / 32;

  int rowin = lane >> 2;
  int csrc = (lane & 3) ^ (rowin & 3);

  auto stage = [&](int t, int buf) {
    int kt = t * 32;
#pragma unroll
    for (int j = 0; j < 2; ++j) {
      int r = w * 2 + j;
      int tr = r * 16 + rowin;
      async_cp16(A + (size_t)(mrow + tr) * K + kt + 8 * csrc, lds + buf * 8192 + r * 1024);
    }
#pragma unroll
    for (int j = 0; j < 2; ++j) {
      int r = w * 2 + j;
      int tr = r * 16 + rowin;
      async_cp16(B + (size_t)(bn * 128 + tr) * K + kt + 8 * csrc, lds + 16384 + buf * 8192 + r * 1024);
    }
  };

  f32x4 acc[4][4] = {};
  stage(0, 0);
  asm volatile("s_waitcnt vmcnt(0)" ::: "memory");
  __builtin_amdgcn_s_barrier();
  asm volatile("" ::: "memory");

  for (int t = 0; t < NKT; ++t) {
    int cur = t & 1;
    bool pre = (t + 1 < NKT);
    if (pre) stage(t + 1, cur ^ 1);
    const char* Ac = lds + cur * 8192;
    const char* Bc = lds + 16384 + cur * 8192;

    bf16x8 af[4], bfv[4];
#pragma unroll
    for (int mi = 0; mi < 4; ++mi) {
      int row = wm * 64 + mi * 16 + li;
      af[mi] = __builtin_bit_cast(bf16x8, *(const u32x4*)(Ac + row * 64 + (g ^ (row & 3)) * 16));
    }
#pragma unroll
    for (int ni = 0; ni < 4; ++ni) {
      int row = wn * 64 + ni * 16 + li;
      bfv[ni] = __builtin_bit_cast(bf16x8, *(const u32x4*)(Bc + row * 64 + (g ^ (row & 3)) * 16));
    }
    __builtin_amdgcn_s_setprio(1);
#pragma unroll
    for (int mi = 0; mi < 4; ++mi)
#pragma unroll
      for (int ni = 0; ni < 4; ++ni)
        acc[mi][ni] = __builtin_amdgcn_mfma_f32_16x16x32_bf16(af[mi], bfv[ni], acc[mi][ni], 0, 0, 0);
    __builtin_amdgcn_s_setprio(0);

    if (pre) asm volatile("s_waitcnt vmcnt(0)" ::: "memory");
    __builtin_amdgcn_s_barrier();
    asm volatile("" ::: "memory");
  }

#pragma unroll
  for (int mi = 0; mi < 4; ++mi) {
#pragma unroll
    for (int ni = 0; ni < 4; ++ni) {
      int col = bn * 128 + wn * 64 + ni * 16 + li;
      float bv = bias[col];
#pragma unroll
      for (int i = 0; i < 4; ++i) {
        int r = mrow + wm * 64 + mi * 16 + 4 * g + i;
        C[(size_t)r * N + col] = acc[mi][ni][i] + bv;
      }
    }
  }
}

// ---------------- merged postprocess + V transpose ----------------
__global__ __launch_bounds__(256) void k_postvt(
    const uint16_t* __restrict__ qkv_img, const uint16_t* __restrict__ qkv_txt,
    const float* __restrict__ fcos, const float* __restrict__ fsin,
    const float* __restrict__ wq, const float* __restrict__ wk,
    const float* __restrict__ waq, const float* __restrict__ wak,
    uint16_t* __restrict__ Qo, uint16_t* __restrict__ Ko, uint16_t* __restrict__ VTo) {
  __shared__ uint16_t Vl[64][136];   // used by VT branch only
  if (blockIdx.x < S_ALL) {
    int s = blockIdx.x;
    const uint16_t* row = (s < S_TXT) ? qkv_txt + (size_t)s * N_QKV
                                      : qkv_img + (size_t)(s - S_TXT) * N_QKV;
    const float* wqp = (s < S_TXT) ? waq : wq;
    const float* wkp = (s < S_TXT) ? wak : wk;
    int lane = threadIdx.x & 63, w = threadIdx.x >> 6;
    int h = w * 4 + (lane >> 4);
    int d0 = (lane & 15) * 8;
    float cs[8], sn[8];
#pragma unroll
    for (int j = 0; j < 8; ++j) {
      cs[j] = fcos[s * HD + d0 + j];
      sn[j] = fsin[s * HD + d0 + j];
    }
#pragma unroll
    for (int part = 0; part < 2; ++part) {  // 0 = Q, 1 = K
      const uint16_t* src = row + part * INNER + h * HD + d0;
      u32x4 raw = *(const u32x4*)src;
      const uint16_t* rp = (const uint16_t*)&raw;
      float x[8], ss = 0.f;
#pragma unroll
      for (int j = 0; j < 8; ++j) { x[j] = bf2f(rp[j]); ss += x[j] * x[j]; }
      ss += __shfl_xor(ss, 1); ss += __shfl_xor(ss, 2);
      ss += __shfl_xor(ss, 4); ss += __shfl_xor(ss, 8);
      float rn = rsqrtf(ss * (1.0f / HD) + ATT_EPS);
      const float* wp = part ? wkp : wqp;
#pragma unroll
      for (int j = 0; j < 8; ++j) x[j] = x[j] * rn * wp[d0 + j];
      float y[8];
#pragma unroll
      for (int j = 0; j < 8; j += 2) {
        y[j]     = x[j] * cs[j] - x[j + 1] * sn[j];
        y[j + 1] = x[j + 1] * cs[j + 1] + x[j] * sn[j + 1];
      }
      float sc = part ? 1.0f : (ATT_SCALE * LOG2E);
      uint16_t ov[8];
#pragma unroll
      for (int j = 0; j < 8; ++j) ov[j] = f2bf(y[j] * sc);
      uint16_t* dst = (part ? Ko : Qo) + ((size_t)h * S_ALL + s) * HD + d0;
      *(u32x4*)dst = *(const u32x4*)ov;
    }
  } else {
    int b = blockIdx.x - S_ALL;
    int st = b % 36, h = b / 36;
    int s0 = st * 64;
    const uint16_t* base = (s0 < S_TXT) ? qkv_txt + (size_t)s0 * N_QKV
                                        : qkv_img + (size_t)(s0 - S_TXT) * N_QKV;
    base += 2 * INNER + h * HD;
    int tid = threadIdx.x;
#pragma unroll
    for (int it = 0; it < 4; ++it) {
      int idx = it * 256 + tid;
      int r = idx >> 4, c = idx & 15;
      *(u32x4*)&Vl[r][c * 8] = *(const u32x4*)(base + (size_t)r * N_QKV + c * 8);
    }
    __syncthreads();
#pragma unroll
    for (int it = 0; it < 4; ++it) {
      int idx = it * 256 + tid;
      int d = idx >> 3, sc = (idx & 7) * 8;
      uint16_t tmp[8];
#pragma unroll
      for (int j = 0; j < 8; ++j) tmp[j] = Vl[sc + j][d];
      *(u32x4*)&VTo[((size_t)h * HD + d) * S_ALL + s0 + sc] = *(const u32x4*)tmp;
    }
  }
}

// ---------------- attention (R11 winner: split-KV x4, bf16 partials, cvt_pk P-pack) ----------------
__global__ __launch_bounds__(256, 3) void k_attn(
    const uint16_t* __restrict__ Qg, const uint16_t* __restrict__ Kg,
    const uint16_t* __restrict__ VTg,
    uint16_t* __restrict__ part0, uint16_t* __restrict__ part1,
    uint16_t* __restrict__ part2, uint16_t* __restrict__ part3,
    float* __restrict__ lsumP) {
  __shared__ __align__(16) char Kt[2][8192];       // [32 key][128 d], chunk^=(row&15)
  __shared__ __align__(16) char Vt[2][8192];       // [128 d][32 s], chunk^=((row>>1)&3)
  __shared__ __align__(16) uint16_t Pl[4][32 * 40];  // per wave: [32 q][32 key + pad]

  int b0 = blockIdx.x;
  int bid = (b0 & 7) * 144 + (b0 >> 3);  // XCD-chunked: 2 heads per XCD
  int h = bid / 72, r6 = bid % 72, sp = r6 / 18, qt = r6 % 18;
  int tid = threadIdx.x, lane = tid & 63, w = tid >> 6;
  int g = lane >> 4, li = lane & 15;

  const uint16_t* Kh = Kg + (size_t)h * S_ALL * HD;
  const uint16_t* Vh = VTg + (size_t)h * HD * S_ALL;
  uint16_t* po = (sp & 2) ? ((sp & 1) ? part3 : part2) : ((sp & 1) ? part1 : part0);
  po += ((size_t)(h * QT_N + qt) * 128 + w * 32) * 128;

  int qbase = qt * 128 + w * 32;
  bf16x8 qf[2][4];
#pragma unroll
  for (int q2 = 0; q2 < 2; ++q2) {
    const uint16_t* qp = Qg + ((size_t)h * S_ALL + qbase + q2 * 16 + li) * HD;
#pragma unroll
    for (int kc = 0; kc < 4; ++kc)
      qf[q2][kc] = __builtin_bit_cast(bf16x8, *(const u32x4*)(qp + kc * 32 + g * 8));
  }
  f32x4 o[2][8] = {};
  float lsum[2] = {0.f, 0.f};

  auto stage = [&](int tk, int buf) {
#pragma unroll
    for (int j = 0; j < 2; ++j) {
      int cj = w * 128 + j * 64 + lane;
      int row = cj >> 4, c = (cj & 15) ^ (row & 15);
      async_cp16(Kh + (size_t)(tk * 32 + row) * HD + 8 * c, Kt[buf] + (w * 128 + j * 64) * 16);
    }
#pragma unroll
    for (int j = 0; j < 2; ++j) {
      int cj = w * 128 + j * 64 + lane;
      int row = cj >> 2, c = (cj & 3) ^ ((row >> 1) & 3);
      async_cp16(Vh + (size_t)row * S_ALL + tk * 32 + 8 * c, Vt[buf] + (w * 128 + j * 64) * 16);
    }
  };

  int t0 = sp * TPS;
  stage(t0, 0);
  asm volatile("s_waitcnt vmcnt(0)" ::: "memory");
  __builtin_amdgcn_s_barrier();
  asm volatile("" ::: "memory");

  for (int t = 0; t < TPS; ++t) {
    int cur = t & 1;
    if (t + 1 < TPS) stage(t0 + t + 1, cur ^ 1);
    const char* KtC = Kt[cur];
    const char* VtC = Vt[cur];

    f32x4 sc[2][2];
#pragma unroll
    for (int q2 = 0; q2 < 2; ++q2)
#pragma unroll
      for (int kb = 0; kb < 2; ++kb)
        sc[q2][kb] = (f32x4){-MBOUND, -MBOUND, -MBOUND, -MBOUND};
    __builtin_amdgcn_s_setprio(1);
#pragma unroll
    for (int kb = 0; kb < 2; ++kb)
#pragma unroll
      for (int kc = 0; kc < 4; ++kc) {
        int ch = (kc * 4 + g) ^ li;
        bf16x8 kf = __builtin_bit_cast(bf16x8,
            *(const u32x4*)(KtC + (kb * 16 + li) * 256 + ch * 16));
        sc[0][kb] = __builtin_amdgcn_mfma_f32_16x16x32_bf16(kf, qf[0][kc], sc[0][kb], 0, 0, 0);
        sc[1][kb] = __builtin_amdgcn_mfma_f32_16x16x32_bf16(kf, qf[1][kc], sc[1][kb], 0, 0, 0);
      }
    __builtin_amdgcn_s_setprio(0);

    uint16_t* Pw = &Pl[w][0];
#pragma unroll
    for (int q2 = 0; q2 < 2; ++q2)
#pragma unroll
      for (int kb = 0; kb < 2; ++kb) {
        float p0 = fexp2(sc[q2][kb][0]);
        float p1 = fexp2(sc[q2][kb][1]);
        float p2 = fexp2(sc[q2][kb][2]);
        float p3 = fexp2(sc[q2][kb][3]);
        lsum[q2] += (p0 + p1) + (p2 + p3);
        uint2 pk;
        pk.x = cvt_pk_bf16(p0, p1);
        pk.y = cvt_pk_bf16(p2, p3);
        *(uint2*)((char*)Pw + (q2 * 16 + li) * 80 + kb * 32 + g * 8) = pk;
      }

    bf16x8 pf[2];
#pragma unroll
    for (int q2 = 0; q2 < 2; ++q2)
      pf[q2] = __builtin_bit_cast(bf16x8,
          *(const u32x4*)((const char*)Pw + (q2 * 16 + li) * 80 + g * 16));
    __builtin_amdgcn_s_setprio(1);
#pragma unroll
    for (int db = 0; db < 8; ++db) {
      int vrow = db * 16 + li;
      int ch = g ^ ((vrow >> 1) & 3);
      bf16x8 vf = __builtin_bit_cast(bf16x8, *(const u32x4*)(VtC + vrow * 64 + ch * 16));
      o[0][db] = __builtin_amdgcn_mfma_f32_16x16x32_bf16(pf[0], vf, o[0][db], 0, 0, 0);
      o[1][db] = __builtin_amdgcn_mfma_f32_16x16x32_bf16(pf[1], vf, o[1][db], 0, 0, 0);
    }
    __builtin_amdgcn_s_setprio(0);

    asm volatile("s_waitcnt vmcnt(0)" ::: "memory");
    __builtin_amdgcn_s_barrier();
    asm volatile("" ::: "memory");
  }

#pragma unroll
  for (int q2 = 0; q2 < 2; ++q2) {
    float v = lsum[q2];
    v += __shfl_xor(v, 16);
    v += __shfl_xor(v, 32);
    lsum[q2] = v;
  }
  if (lane < 16) {
#pragma unroll
    for (int q2 = 0; q2 < 2; ++q2)
      lsumP[((size_t)sp * HEADS + h) * S_ALL + qbase + q2 * 16 + lane] = lsum[q2];
  }
  // bf16 partial O: row = q2*16+4g+i, col = db*16+li
#pragma unroll
  for (int q2 = 0; q2 < 2; ++q2)
#pragma unroll
    for (int db = 0; db < 8; ++db)
#pragma unroll
      for (int i = 0; i < 4; ++i)
        po[(q2 * 16 + 4 * g + i) * 128 + db * 16 + li] = f2bf(o[q2][db][i]);
}

// combine (16B vectorized): attn[q][h*128+d] = bf16(sum(parts) / sum(lsums))
__global__ __launch_bounds__(256) void k_comb(
    const uint16_t* __restrict__ p0, const uint16_t* __restrict__ p1,
    const uint16_t* __restrict__ p2, const uint16_t* __restrict__ p3,
    const float* __restrict__ lsumP, uint16_t* __restrict__ attn) {
  int q = blockIdx.x, qt = q >> 7, ql = q & 127;
  int d = threadIdx.x * 8, h = d >> 7, dl = d & 127;
  size_t off = (((size_t)h * QT_N + qt) * 128 + ql) * 128 + dl;
  u32x4 a = *(const u32x4*)&p0[off];
  u32x4 b = *(const u32x4*)&p1[off];
  u32x4 c = *(const u32x4*)&p2[off];
  u32x4 e = *(const u32x4*)&p3[off];
  const uint16_t* ap = (const uint16_t*)&a;
  const uint16_t* bp = (const uint16_t*)&b;
  const uint16_t* cp = (const uint16_t*)&c;
  const uint16_t* ep = (const uint16_t*)&e;
  float l = 0.f;
#pragma unroll
  for (int s = 0; s < 4; ++s)
    l += lsumP[((size_t)s * HEADS + h) * S_ALL + q];
  float inv = 1.0f / l;
  uint16_t ov[8];
#pragma unroll
  for (int j = 0; j < 8; ++j)
    ov[j] = f2bf((bf2f(ap[j]) + bf2f(bp[j]) + bf2f(cp[j]) + bf2f(ep[j])) * inv);
  *(u32x4*)&attn[(size_t)q * INNER + d] = *(const u32x4*)ov;
}

// ---------------- launch ----------------
extern "C" void kernel_launch(void* const* d_in, const int* in_sizes, int n_in,
                              void* d_out, int out_size, void* d_ws, size_t ws_size,
                              hipStream_t stream) {
  const float* hidden = (const float*)d_in[0];
  const float* enc    = (const float*)d_in[1];
  const float* fcos   = (const float*)d_in[2];
  const float* fsin   = (const float*)d_in[3];
  const float* Wqkv   = (const float*)d_in[4];
  const float* Wqkva  = (const float*)d_in[5];
  const float* bqkva  = (const float*)d_in[6];
  const float* nqw    = (const float*)d_in[7];
  const float* nkw    = (const float*)d_in[8];
  const float* naqw   = (const float*)d_in[9];
  const float* nakw   = (const float*)d_in[10];
  const float* Wout   = (const float*)d_in[11];
  const float* bout   = (const float*)d_in[12];
  const float* Wadd   = (const float*)d_in[13];
  const float* badd   = (const float*)d_in[14];
  float* out_img = (float*)d_out;
  float* out_enc = (float*)d_out + (size_t)S_IMG * DMODEL;

  char* ws = (char*)d_ws;
  size_t off = 0;
  auto alloc = [&](size_t bytes) {
    char* p = ws + off;
    off += (bytes + 255) & ~(size_t)255;
    return p;
  };
  uint16_t* hs_bf   = (uint16_t*)alloc((size_t)S_IMG * DMODEL * 2);
  uint16_t* enc_bf  = (uint16_t*)alloc((size_t)S_TXT * DMODEL * 2);
  char*     wqkv_base = alloc((size_t)N_QKV * DMODEL * 2 * 2);  // WqkvT + WqkvaT (reused later)
  uint16_t* WqkvT   = (uint16_t*)wqkv_base;
  uint16_t* WqkvaT  = (uint16_t*)(wqkv_base + (size_t)N_QKV * DMODEL * 2);
  uint16_t* WoutT   = (uint16_t*)alloc((size_t)DMODEL * INNER * 2);
  uint16_t* WaddT   = (uint16_t*)alloc((size_t)DMODEL * INNER * 2);
  uint16_t* qkv_img = (uint16_t*)alloc((size_t)S_IMG * N_QKV * 2);
  uint16_t* qkv_txt = (uint16_t*)alloc((size_t)S_TXT * N_QKV * 2);
  // overlay Q/K/VT/attn on the Wqkv(T) region (dead after qkv GEMM)
  uint16_t* Qb   = (uint16_t*)wqkv_base;
  uint16_t* Kb   = Qb + (size_t)HEADS * S_ALL * HD;
  uint16_t* VTb  = Kb + (size_t)HEADS * S_ALL * HD;
  uint16_t* attn = VTb + (size_t)HEADS * S_ALL * HD;
  // bf16 partials: splits 0,1 -> d_out; splits 2,3 -> dead qkv_img
  uint16_t* part0 = (uint16_t*)d_out;
  uint16_t* part1 = part0 + (size_t)S_ALL * INNER;
  uint16_t* part2 = (uint16_t*)qkv_img;
  uint16_t* part3 = part2 + (size_t)S_ALL * INNER;
  float* lsumP = (float*)enc_bf;         // dead after qkv GEMM

  k_prep<<<9344, 256, 0, stream>>>(Wqkv, WqkvT, Wqkva, WqkvaT, Wout, WoutT, Wadd, WaddT,
                                   hidden, hs_bf, S_IMG * DMODEL / 4,
                                   enc, enc_bf, S_TXT * DMODEL / 4);

  dim3 gq(N_QKV / 256, (S_TXT + S_IMG) / 256);
  k_gemm2<<<gq, 512, 0, stream>>>(enc_bf, WqkvaT, bqkva, qkv_txt,
                                  hs_bf, WqkvT, nullptr, qkv_img,
                                  1, N_QKV, DMODEL);

  k_postvt<<<S_ALL + 36 * HEADS, 256, 0, stream>>>(qkv_img, qkv_txt, fcos, fsin,
                                                   nqw, nkw, naqw, nakw, Qb, Kb, VTb);

  k_attn<<<HEADS * QT_N * 4, 256, 0, stream>>>(Qb, Kb, VTb, part0, part1, part2, part3, lsumP);
  k_comb<<<S_ALL, 256, 0, stream>>>(part0, part1, part2, part3, lsumP, attn);

  dim3 go(DMODEL / 128, S_ALL / 128);
  k_gemmO<<<go, 256, 0, stream>>>(attn, WaddT, badd, out_enc,
                                  attn + (size_t)S_TXT * INNER, WoutT, bout, out_img,
                                  2, DMODEL, DMODEL);
}